// Round 1
// baseline (395.669 us; speedup 1.0000x reference)
//
#include <hip/hip_runtime.h>
#include <math.h>

// MultilabelCrossEntropyLoss: B=65536 rows, L=1024, X=32 labels (+1 count col).
// loss = mean_b( -log( sum_{j<n_b} prd[b, labels[b,j]] + 1e-6 ) )
//
// Strategy: 32 lanes per row. Coalesced tgt read (32 consecutive ints per
// group), random gather from the row's 4KB slice of prd, shfl-xor reduce
// within the 32-lane group, block reduce in LDS, one atomicAdd per block.

#define NROWS   65536
#define LCOLS   1024
#define TGT_LD  33          // 32 labels + n
#define TOLV    1e-6f
#define INV_B   (1.0f / 65536.0f)

__global__ __launch_bounds__(256)
void mlce_kernel(const float* __restrict__ prd,
                 const int*   __restrict__ tgt,
                 float*       __restrict__ out)
{
    const int tid = blockIdx.x * blockDim.x + threadIdx.x;
    const int row = tid >> 5;        // 32 lanes per row
    const int j   = tid & 31;

    float loss = 0.0f;
    if (row < NROWS) {
        const int base = row * TGT_LD;
        const int n    = tgt[base + 32];        // broadcast (same addr, no conflict)
        float v = 0.0f;
        if (j < n) {
            const int lab = tgt[base + j];      // coalesced 128B per 32-lane group
            v = prd[row * LCOLS + lab];         // random gather within 4KB row
        }
        // reduce s over the 32-lane group
        #pragma unroll
        for (int off = 16; off > 0; off >>= 1)
            v += __shfl_xor(v, off, 32);
        if (j == 0)
            loss = -logf(v + TOLV);
    }

    // reduce loss across the full 64-lane wave (two rows' losses per wave)
    #pragma unroll
    for (int off = 32; off > 0; off >>= 1)
        loss += __shfl_xor(loss, off, 64);

    __shared__ float smem[4];                   // 4 waves per 256-thread block
    const int wid  = threadIdx.x >> 6;
    const int lane = threadIdx.x & 63;
    if (lane == 0) smem[wid] = loss;
    __syncthreads();
    if (threadIdx.x == 0) {
        const float t = smem[0] + smem[1] + smem[2] + smem[3];
        atomicAdd(out, t * INV_B);              // pre-scaled by 1/B
    }
}

extern "C" void kernel_launch(void* const* d_in, const int* in_sizes, int n_in,
                              void* d_out, int out_size, void* d_ws, size_t ws_size,
                              hipStream_t stream)
{
    const float* prd = (const float*)d_in[0];
    const int*   tgt = (const int*)d_in[1];
    float*       out = (float*)d_out;

    // d_out is re-poisoned to 0xAA before every timed launch: zero it first.
    hipMemsetAsync(out, 0, sizeof(float), stream);

    const int threads = 256;
    const int total   = NROWS * 32;             // 32 lanes per row
    const int blocks  = total / threads;        // 8192
    mlce_kernel<<<blocks, threads, 0, stream>>>(prd, tgt, out);
}